// Round 7
// baseline (949.646 us; speedup 1.0000x reference)
//
#include <hip/hip_runtime.h>
#include <stdint.h>

// ---- problem constants (from reference) ----
#define N_NODES 16000
#define B_      32
#define NPG_    500
#define E_      256000
#define F_      1024
#define OD_     128
#define DD_     80
#define TD_     32
#define NH_     4
#define DH_     8
#define DFF_    128
#define LSUB_   128
#define MAXLEN_ 512
#define EPS_    1e-5f
#define SLOPE_  0.01f

typedef __bf16 bf16x8 __attribute__((ext_vector_type(8)));
typedef float  f32x4  __attribute__((ext_vector_type(4)));

__device__ __forceinline__ float leaky(float v) { return v >= 0.f ? v : SLOPE_ * v; }

__device__ __forceinline__ unsigned short f2bf(float f) {
  unsigned u = __float_as_uint(f);
  u += 0x7FFFu + ((u >> 16) & 1u);   // RNE
  return (unsigned short)(u >> 16);
}
__device__ __forceinline__ float bf2f(unsigned short u) {
  return __uint_as_float((unsigned)u << 16);
}

// ---- fp32 -> bf16 conversion for two tensors (grid.y selects) ----
__global__ void k_f2bf2(const float* __restrict__ in0, const float* __restrict__ in1,
                        unsigned short* __restrict__ out0, unsigned short* __restrict__ out1,
                        int n4) {
  const float* in = blockIdx.y ? in1 : in0;
  unsigned short* out = blockIdx.y ? out1 : out0;
  int i = blockIdx.x * blockDim.x + threadIdx.x;
  int stride = gridDim.x * blockDim.x;
  for (; i < n4; i += stride) {
    float4 v = ((const float4*)in)[i];
    ushort4 o;
    o.x = f2bf(v.x); o.y = f2bf(v.y); o.z = f2bf(v.z); o.w = f2bf(v.w);
    ((ushort4*)out)[i] = o;
  }
}

// ---- bf16 MFMA GEMM: C[M,N] = A[M,K]*B[N,K]^T, bf16 out.
// BARRIER-FREE: no LDS. Each lane loads its MFMA fragments directly from
// global (16B dwordx4 per fragment; a wave touches 16 rows x 64B segments).
// Register ping-pong: load frags for kt+1 while MFMA-ing kt; fully unrolled
// K-loop lets the compiler interleave loads and MFMA under vmcnt(N>0) —
// the AITER/hipBLASLt pattern the 2-barrier LDS loop cannot express
// (rounds 5/6: barrier vmcnt(0) drain pinned MfmaUtil at ~19%).
// XCD swizzle kept: 8 consecutive-linear blocks = 8 nIdx of one mIdx on one
// XCD => A fetched from HBM ~once (round-5 verified: FETCH 284->65 MB).
__global__ __launch_bounds__(256) void k_gemm_bf16(const unsigned short* __restrict__ A,
                                                   const unsigned short* __restrict__ Bw,
                                                   unsigned short* __restrict__ C) {
  const int K = 1024, N = 1024;
  const int id = blockIdx.x;
  const int g  = id >> 10;
  const int l  = id & 1023;
  const int xcd = l & 7;
  const int j   = l >> 3;                 // 0..127
  const int mIdx = xcd + 8 * (j >> 3);    // 0..127
  const int nIdx = j & 7;
  if (mIdx >= 125) return;                // uniform across block (16000 = 125*128)
  A  += (size_t)g * N_NODES * K;
  Bw += (size_t)g * K * N;
  C  += (size_t)g * N_NODES * N;
  const int t    = threadIdx.x;
  const int lane = t & 63, wave = t >> 6;
  const int wrow = wave >> 1, wcol = wave & 1;
  const int quad = lane >> 4, l15 = lane & 15;
  const int mBase = mIdx * 128;
  const int nBase = nIdx * 128;

  const unsigned short* aP[4];
  const unsigned short* bP[4];
#pragma unroll
  for (int i = 0; i < 4; ++i) {
    aP[i] = &A[(size_t)(mBase + wrow * 64 + i * 16 + l15) * K + quad * 8];
    bP[i] = &Bw[(size_t)(nBase + wcol * 64 + i * 16 + l15) * K + quad * 8];
  }

  f32x4 acc[4][4];
  f32x4 zero = {0.f, 0.f, 0.f, 0.f};
#pragma unroll
  for (int i = 0; i < 4; ++i)
#pragma unroll
    for (int jj = 0; jj < 4; ++jj) acc[i][jj] = zero;

  bf16x8 aR[2][4], bR[2][4];
#pragma unroll
  for (int i = 0; i < 4; ++i) {
    aR[0][i] = *(const bf16x8*)aP[i];
    bR[0][i] = *(const bf16x8*)bP[i];
  }

#pragma unroll
  for (int kt = 0; kt < 32; ++kt) {
    const int cur = kt & 1, nxt = cur ^ 1;
    if (kt < 31) {
      const int off = (kt + 1) * 32;
#pragma unroll
      for (int i = 0; i < 4; ++i) {
        aR[nxt][i] = *(const bf16x8*)(aP[i] + off);
        bR[nxt][i] = *(const bf16x8*)(bP[i] + off);
      }
    }
#pragma unroll
    for (int ti = 0; ti < 4; ++ti)
#pragma unroll
      for (int tj = 0; tj < 4; ++tj)
        acc[ti][tj] = __builtin_amdgcn_mfma_f32_16x16x32_bf16(aR[cur][ti], bR[cur][tj],
                                                              acc[ti][tj], 0, 0, 0);
  }

#pragma unroll
  for (int ti = 0; ti < 4; ++ti)
#pragma unroll
    for (int tj = 0; tj < 4; ++tj)
#pragma unroll
      for (int r = 0; r < 4; ++r) {
        int grow = mBase + wrow * 64 + ti * 16 + quad * 4 + r;
        int gcol = nBase + wcol * 64 + tj * 16 + l15;
        C[(size_t)grow * N + gcol] = f2bf(acc[ti][tj][r]);
      }
}

// ---- degree histogram over dst (grid.y = graph) ----
__global__ void k_hist(const int* __restrict__ ei0, const int* __restrict__ ei1,
                       int* __restrict__ cnt, int e, int n) {
  const int g = blockIdx.y;
  const int* dst = (g ? ei1 : ei0) + e;
  int i = blockIdx.x * 256 + threadIdx.x;
  if (i < e) atomicAdd(&cnt[g * n + dst[i]], 1);
}

// ---- per-graph block: exclusive scan of cnt -> rowstart/cursor; dinv = rsqrt(cnt+1) ----
__global__ void k_scan(const int* __restrict__ cnt_all, int* __restrict__ rowstart_all,
                       int* __restrict__ cursor_all, float* __restrict__ dinv_all, int n) {
  const int g = blockIdx.x;
  const int* cnt = cnt_all + g * n;
  int* rowstart = rowstart_all + g * (n + 1);
  int* cursor   = cursor_all + g * n;
  float* dinv   = dinv_all + g * n;
  __shared__ int part[256];
  __shared__ int base[257];
  int t = threadIdx.x;
  int chunk = (n + 255) >> 8;
  int s = 0;
  for (int j = 0; j < chunk; ++j) {
    int idx = t * chunk + j;
    if (idx < n) s += cnt[idx];
  }
  part[t] = s;
  __syncthreads();
  if (t == 0) {
    int a = 0;
    for (int i = 0; i < 256; ++i) { base[i] = a; a += part[i]; }
    base[256] = a;
  }
  __syncthreads();
  int a = base[t];
  for (int j = 0; j < chunk; ++j) {
    int idx = t * chunk + j;
    if (idx < n) {
      int c = cnt[idx];
      rowstart[idx] = a; cursor[idx] = a; a += c;
      dinv[idx] = rsqrtf((float)c + 1.0f);
    }
  }
  if (t == 0) rowstart[n] = base[256];
}

// ---- scatter edges to CSR, precomputing edge weight dinv[s]*dinv[d] (grid.y = graph) ----
__global__ void k_scatter(const int* __restrict__ ei0, const int* __restrict__ ei1,
                          const float* __restrict__ dinv_all, int* __restrict__ cursor_all,
                          int* __restrict__ csr_all, float* __restrict__ csrw_all,
                          int e, int n) {
  const int g = blockIdx.y;
  const int* ei = g ? ei1 : ei0;
  int i = blockIdx.x * 256 + threadIdx.x;
  if (i < e) {
    int s = ei[i], d = ei[e + i];
    int p = atomicAdd(&cursor_all[g * n + d], 1);
    csr_all[(size_t)g * e + p]  = s;
    csrw_all[(size_t)g * e + p] = dinv_all[g * n + s] * dinv_all[g * n + d];
  }
}

// ---- sliced CSR gather: grid (8 slices, 16000 dst). slice == linear%8 -> stable XCD
//      under round-robin dispatch => per-XCD h working set = 4 MB (L2-resident). ----
__global__ __launch_bounds__(64) void k_gather(const ushort2* __restrict__ h2,
                                               const float* __restrict__ dinv,
                                               const int* __restrict__ rowstart,
                                               const int* __restrict__ csr,
                                               const float* __restrict__ csrw,
                                               ushort2* __restrict__ agg2) {
  const int sl = blockIdx.x;   // 0..7 feature slice (128 features = 64 ushort2)
  const int i  = blockIdx.y;   // dst node
  const int t  = threadIdx.x;  // 64
  __shared__ int   ssrc[64];
  __shared__ float sw[64];
  const float di = dinv[i];
  const size_t fo = (size_t)sl * 64 + t;
  ushort2 sv = h2[(size_t)i * 512 + fo];
  const float selfw = di * di;
  float ax = bf2f(sv.x) * selfw, ay = bf2f(sv.y) * selfw;
  const int beg = rowstart[i], end = rowstart[i + 1];
  for (int base = beg; base < end; base += 64) {
    int c = end - base; if (c > 64) c = 64;
    __syncthreads();
    if (t < c) { ssrc[t] = csr[base + t]; sw[t] = csrw[base + t]; }
    __syncthreads();
    int j = 0;
    for (; j + 4 <= c; j += 4) {
      ushort2 v0 = h2[(size_t)ssrc[j]     * 512 + fo];
      ushort2 v1 = h2[(size_t)ssrc[j + 1] * 512 + fo];
      ushort2 v2 = h2[(size_t)ssrc[j + 2] * 512 + fo];
      ushort2 v3 = h2[(size_t)ssrc[j + 3] * 512 + fo];
      float w0 = sw[j], w1 = sw[j + 1], w2 = sw[j + 2], w3 = sw[j + 3];
      ax += bf2f(v0.x) * w0 + bf2f(v1.x) * w1 + bf2f(v2.x) * w2 + bf2f(v3.x) * w3;
      ay += bf2f(v0.y) * w0 + bf2f(v1.y) * w1 + bf2f(v2.y) * w2 + bf2f(v3.y) * w3;
    }
    for (; j < c; ++j) {
      ushort2 v0 = h2[(size_t)ssrc[j] * 512 + fo];
      float w0 = sw[j];
      ax += bf2f(v0.x) * w0; ay += bf2f(v0.y) * w0;
    }
  }
  ushort2 o; o.x = f2bf(ax); o.y = f2bf(ay);
  agg2[(size_t)i * 512 + fo] = o;
}

// ---- mean pool of leaky(agg + bias); grid.z in [0,64): g = z>>5, b = z&31 ----
__global__ void k_pool(const unsigned short* __restrict__ agg_all,
                       const float* __restrict__ bias0, const float* __restrict__ bias1,
                       float* __restrict__ pooled_all) {
  int f = blockIdx.x * 256 + threadIdx.x;  // 0..1023
  int z = blockIdx.z;
  int g = z >> 5, b = z & 31;
  const unsigned short* agg = agg_all + (size_t)g * N_NODES * F_;
  const float* bias = g ? bias1 : bias0;
  float* pooled = pooled_all + (size_t)g * B_ * F_;
  int r0 = blockIdx.y * 100;
  float bf = bias[f];
  float s = 0.f;
  for (int r = 0; r < 100; ++r)
    s += leaky(bf2f(agg[(size_t)(b * NPG_ + r0 + r) * F_ + f]) + bf);
  atomicAdd(&pooled[b * F_ + f], s);
}

// ---- fc (grid.y = graph) ----
__global__ void k_fc(const float* __restrict__ pooled_all,
                     const float* __restrict__ w0, const float* __restrict__ w1,
                     const float* __restrict__ bias0, const float* __restrict__ bias1,
                     float* __restrict__ out0, float* __restrict__ out1) {
  int b = blockIdx.x, o = threadIdx.x, g = blockIdx.y;
  const float* p  = pooled_all + (size_t)g * B_ * F_ + b * F_;
  const float* wr = (g ? w1 : w0) + o * F_;
  const float* bias = g ? bias1 : bias0;
  float* out = g ? out1 : out0;
  float acc = 0.f;
  for (int f = 0; f < F_; ++f) acc += p[f] * wr[f];
  out[b * OD_ + o] = leaky(acc * (1.f / 500.f) + bias[o]);
}

// ---- ragged pack ----
__global__ void k_pack(const float* __restrict__ m0, const float* __restrict__ m1,
                       const float* __restrict__ m2, const float* __restrict__ m3,
                       const int* __restrict__ l0, const int* __restrict__ l1,
                       const int* __restrict__ l2, const int* __restrict__ l3,
                       const float* __restrict__ rw, const float* __restrict__ rb,
                       float* __restrict__ seq) {
  __shared__ float xs[DD_];
  const int p = blockIdx.x, b = blockIdx.y, k = blockIdx.z;
  const float* mas = (k == 0) ? m0 : (k == 1) ? m1 : (k == 2) ? m2 : m3;
  const int*   lk  = (k == 0) ? l0 : (k == 1) ? l1 : (k == 2) ? l2 : l3;
  const int len = lk[b];
  if (p >= len) return;
  int off = 0;
  if (k > 0) off += l0[b];
  if (k > 1) off += l1[b];
  if (k > 2) off += l2[b];
  const int t = threadIdx.x;  // 64
  for (int d = t; d < DD_; d += 64) xs[d] = mas[(size_t)(b * LSUB_ + p) * DD_ + d];
  __syncthreads();
  if (t < TD_) {
    float v;
    if (t < TD_ - 2) {
      float a = rb[t];
      const float* w = &rw[t * DD_];
      for (int d = 0; d < DD_; ++d) a += xs[d] * w[d];
      v = a;
    } else if (t == TD_ - 2) {
      v = (k == 0 || k == 2) ? 1.f : 0.f;
    } else {
      v = (k < 2) ? 1.f : 0.f;
    }
    seq[((size_t)b * MAXLEN_ + off + p) * TD_ + t] = v;
  }
}

__global__ void k_totlen(const int* __restrict__ l0, const int* __restrict__ l1,
                         const int* __restrict__ l2, const int* __restrict__ l3,
                         int* __restrict__ tot) {
  int b = threadIdx.x;
  if (b < B_) tot[b] = l0[b] + l1[b] + l2[b] + l3[b];
}

// ---- qkv projection (skip dead rows) ----
__global__ void k_qkv(const float* __restrict__ xt, const float* __restrict__ w,
                      const float* __restrict__ bias, const int* __restrict__ tot,
                      float* __restrict__ qkv) {
  __shared__ float xs[TD_];
  const int row = blockIdx.x;
  if ((row & (MAXLEN_ - 1)) >= tot[row >> 9]) return;
  const int t = threadIdx.x;      // 128
  if (t < TD_) xs[t] = xt[(size_t)row * TD_ + t];
  __syncthreads();
  if (t < 3 * TD_) {
    float a = bias[t];
    const float* wr = &w[t * TD_];
#pragma unroll
    for (int k = 0; k < TD_; ++k) a += xs[k] * wr[k];
    qkv[(size_t)row * 96 + t] = a;
  }
}

// ---- attention: one lane-pair per query, single pass (scores |s|<~1) ----
__global__ __launch_bounds__(128) void k_attn(const float* __restrict__ qkv,
                                              const int* __restrict__ tot,
                                              float* __restrict__ obuf) {
  __shared__ float Kl[MAXLEN_ * DH_];
  __shared__ float Vl[MAXLEN_ * DH_];
  const int h = blockIdx.x, b = blockIdx.y, qz = blockIdx.z;
  const int t = threadIdx.x;  // 128
  const int L = tot[b];
  if (qz * 64 >= L) return;
  const float* base = &qkv[(size_t)b * MAXLEN_ * 96];
  for (int i = t; i < L * DH_; i += 128) {
    int p = i >> 3, d = i & 7;
    Kl[i] = base[p * 96 + 32 + h * 8 + d];
    Vl[i] = base[p * 96 + 64 + h * 8 + d];
  }
  __syncthreads();
  const int qi = qz * 64 + (t >> 1);
  if (qi >= L) return;
  const int half = t & 1;
  const float scale = 0.35355339059327373f;  // 1/sqrt(8)
  float q[8];
#pragma unroll
  for (int d = 0; d < 8; ++d) q[d] = base[qi * 96 + h * 8 + d] * scale;

  float l0 = 0.f, l1 = 0.f;
  float a0[8] = {0, 0, 0, 0, 0, 0, 0, 0};
  float a1[8] = {0, 0, 0, 0, 0, 0, 0, 0};
  int j = half;
  for (; j + 2 < L; j += 4) {
    const float* kr0 = &Kl[j * 8];
    const float* kr1 = &Kl[(j + 2) * 8];
    float s0 = 0.f, s1 = 0.f;
#pragma unroll
    for (int d = 0; d < 8; ++d) { s0 += q[d] * kr0[d]; s1 += q[d] * kr1[d]; }
    float p0 = __expf(s0), p1 = __expf(s1);
    l0 += p0; l1 += p1;
    const float* vr0 = &Vl[j * 8];
    const float* vr1 = &Vl[(j + 2) * 8];
#pragma unroll
    for (int d = 0; d < 8; ++d) { a0[d] += p0 * vr0[d]; a1[d] += p1 * vr1[d]; }
  }
  for (; j < L; j += 2) {
    const float* kr = &Kl[j * 8];
    float s = 0.f;
#pragma unroll
    for (int d = 0; d < 8; ++d) s += q[d] * kr[d];
    float p = __expf(s);
    l0 += p;
    const float* vr = &Vl[j * 8];
#pragma unroll
    for (int d = 0; d < 8; ++d) a0[d] += p * vr[d];
  }
  float l = l0 + l1;
#pragma unroll
  for (int d = 0; d < 8; ++d) a0[d] += a1[d];
  l += __shfl_xor(l, 1);
#pragma unroll
  for (int d = 0; d < 8; ++d) a0[d] += __shfl_xor(a0[d], 1);
  float inv = 1.f / l;
  const int dbase = half * 4;
  float4 o;
  o.x = a0[dbase + 0] * inv; o.y = a0[dbase + 1] * inv;
  o.z = a0[dbase + 2] * inv; o.w = a0[dbase + 3] * inv;
  *(float4*)&obuf[((size_t)b * MAXLEN_ + qi) * TD_ + h * 8 + dbase] = o;
}

// ---- out-proj + residual + LN1 (skip dead rows) ----
__global__ void k_oproj_ln(const float* __restrict__ obuf, const float* __restrict__ w,
                           const float* __restrict__ bias, const float* __restrict__ lw,
                           const float* __restrict__ lb, const int* __restrict__ tot,
                           float* __restrict__ xt) {
  const int t = threadIdx.x;             // 256
  const int r = blockIdx.x * 8 + (t >> 5);
  if ((r & (MAXLEN_ - 1)) >= tot[r >> 9]) return;
  const int j = t & 31;
  const float* orow = &obuf[(size_t)r * TD_];
  float a = bias[j] + xt[(size_t)r * TD_ + j];
  const float* wr = &w[j * TD_];
#pragma unroll
  for (int k = 0; k < TD_; ++k) a += orow[k] * wr[k];
  float s1 = a, s2 = a * a;
#pragma unroll
  for (int m = 1; m < 32; m <<= 1) {
    s1 += __shfl_xor(s1, m, 32);
    s2 += __shfl_xor(s2, m, 32);
  }
  float mean = s1 * (1.f / 32.f);
  float var  = s2 * (1.f / 32.f) - mean * mean;
  xt[(size_t)r * TD_ + j] = (a - mean) * rsqrtf(var + EPS_) * lw[j] + lb[j];
}

// ---- FFN (relu) + residual + LN2 (skip dead rows) ----
__global__ void k_ffn_ln(const float* __restrict__ w1, const float* __restrict__ b1,
                         const float* __restrict__ w2, const float* __restrict__ b2,
                         const float* __restrict__ lw, const float* __restrict__ lb,
                         const int* __restrict__ tot, float* __restrict__ xt) {
  const int r = blockIdx.x, t = threadIdx.x;  // 128
  if ((r & (MAXLEN_ - 1)) >= tot[r >> 9]) return;
  __shared__ float xs[TD_];
  __shared__ float hb[DFF_];
  if (t < TD_) xs[t] = xt[(size_t)r * TD_ + t];
  __syncthreads();
  {
    float a = b1[t];
    const float* wr = &w1[t * TD_];
#pragma unroll
    for (int k = 0; k < TD_; ++k) a += xs[k] * wr[k];
    hb[t] = fmaxf(a, 0.f);
  }
  __syncthreads();
  if (t < TD_) {
    float a = b2[t] + xs[t];
    const float* wr = &w2[t * DFF_];
#pragma unroll
    for (int k = 0; k < DFF_; ++k) a += hb[k] * wr[k];
    float s1 = a, s2 = a * a;
#pragma unroll
    for (int m = 1; m < 32; m <<= 1) {
      s1 += __shfl_xor(s1, m, 32);
      s2 += __shfl_xor(s2, m, 32);
    }
    float mean = s1 * (1.f / 32.f);
    float var  = s2 * (1.f / 32.f) - mean * mean;
    xt[(size_t)r * TD_ + t] = (a - mean) * rsqrtf(var + EPS_) * lw[t] + lb[t];
  }
}

// ---- masked mean ----
__global__ void k_maskmean(const float* __restrict__ xt, const int* __restrict__ tot,
                           float* __restrict__ mout) {
  __shared__ float sbuf[8][32];
  const int b = blockIdx.x, t = threadIdx.x;  // 256
  const int j = t & 31, c = t >> 5;
  const int L = tot[b];
  float s = 0.f;
  for (int p = c; p < L; p += 8) s += xt[((size_t)b * MAXLEN_ + p) * TD_ + j];
  sbuf[c][j] = s;
  __syncthreads();
  if (t < 32) {
    float a = 0.f;
#pragma unroll
    for (int cc = 0; cc < 8; ++cc) a += sbuf[cc][t];
    mout[b * TD_ + t] = a / (float)L;
  }
}

// ---- final linear ----
__global__ void k_final(const float* __restrict__ x1, const float* __restrict__ x2,
                        const float* __restrict__ mo, const float* __restrict__ fw,
                        const float* __restrict__ fb, float* __restrict__ out) {
  const int b = blockIdx.x, t = threadIdx.x;  // 64
  float s = 0.f;
  for (int i = t; i < 2 * OD_ + TD_; i += 64) {
    float c = (i < OD_) ? x1[b * OD_ + i]
            : (i < 2 * OD_) ? x2[b * OD_ + (i - OD_)]
            : mo[b * TD_ + (i - 2 * OD_)];
    s += fw[i] * c;
  }
#pragma unroll
  for (int m = 1; m < 64; m <<= 1) s += __shfl_xor(s, m, 64);
  if (t == 0) out[b] = s + fb[0];
}

extern "C" void kernel_launch(void* const* d_in, const int* in_sizes, int n_in,
                              void* d_out, int out_size, void* d_ws, size_t ws_size,
                              hipStream_t stream) {
  (void)in_sizes; (void)n_in; (void)out_size; (void)ws_size;
  const float* pro_x[2]  = {(const float*)d_in[0], (const float*)d_in[1]};
  const int*   pro_ei[2] = {(const int*)d_in[2], (const int*)d_in[3]};
  const float* mas[4]    = {(const float*)d_in[6], (const float*)d_in[8],
                            (const float*)d_in[10], (const float*)d_in[12]};
  const int*   lens[4]   = {(const int*)d_in[7], (const int*)d_in[9],
                            (const int*)d_in[11], (const int*)d_in[13]};
  const float* gw[2]  = {(const float*)d_in[14], (const float*)d_in[16]};
  const float* gb[2]  = {(const float*)d_in[15], (const float*)d_in[17]};
  const float* fcw[2] = {(const float*)d_in[18], (const float*)d_in[20]};
  const float* fcb[2] = {(const float*)d_in[19], (const float*)d_in[21]};
  const float* red_w = (const float*)d_in[22];
  const float* red_b = (const float*)d_in[23];
  const float* attn_in_w  = (const float*)d_in[24];
  const float* attn_in_b  = (const float*)d_in[25];
  const float* attn_out_w = (const float*)d_in[26];
  const float* attn_out_b = (const float*)d_in[27];
  const float* ln1_w = (const float*)d_in[28];
  const float* ln1_b = (const float*)d_in[29];
  const float* ln2_w = (const float*)d_in[30];
  const float* ln2_b = (const float*)d_in[31];
  const float* ff1_w = (const float*)d_in[32];
  const float* ff1_b = (const float*)d_in[33];
  const float* ff2_w = (const float*)d_in[34];
  const float* ff2_b = (const float*)d_in[35];
  const float* final_w = (const float*)d_in[36];
  const float* final_b = (const float*)d_in[37];
  float* out = (float*)d_out;

  char* p = (char*)d_ws;
  auto carve = [&](size_t bytes) -> void* {
    void* r = (void*)p;
    p += (bytes + 255) & ~(size_t)255;
    return r;
  };
  unsigned short* xb  = (unsigned short*)carve((size_t)2 * N_NODES * F_ * 2);
  unsigned short* Wb  = (unsigned short*)carve((size_t)2 * F_ * F_ * 2);
  unsigned short* h   = (unsigned short*)carve((size_t)2 * N_NODES * F_ * 2);
  unsigned short* agg = (unsigned short*)carve((size_t)2 * N_NODES * F_ * 2);
  int*   cnt      = (int*)carve((size_t)2 * N_NODES * 4);
  float* dinv     = (float*)carve((size_t)2 * N_NODES * 4);
  int*   rowstart = (int*)carve((size_t)2 * (N_NODES + 1) * 4);
  int*   cursor   = (int*)carve((size_t)2 * N_NODES * 4);
  int*   csr      = (int*)carve((size_t)2 * E_ * 4);
  float* csrw     = (float*)carve((size_t)2 * E_ * 4);
  float* pooled   = (float*)carve((size_t)2 * B_ * F_ * 4);
  float* xg[2];
  xg[0] = (float*)carve((size_t)B_ * OD_ * 4);
  xg[1] = (float*)carve((size_t)B_ * OD_ * 4);
  float* seq    = (float*)carve((size_t)B_ * MAXLEN_ * TD_ * 4);
  float* qkv    = (float*)carve((size_t)B_ * MAXLEN_ * 96 * 4);
  float* obuf   = (float*)carve((size_t)B_ * MAXLEN_ * TD_ * 4);
  int*   totlen = (int*)carve((size_t)B_ * 4);
  float* masout = (float*)carve((size_t)B_ * TD_ * 4);

  // ---- GCN branches (merged across both graphs) ----
  k_f2bf2<<<dim3(1024, 2), 256, 0, stream>>>(pro_x[0], pro_x[1], xb,
                                             xb + (size_t)N_NODES * F_, (N_NODES * F_) / 4);
  k_f2bf2<<<dim3(512, 2), 256, 0, stream>>>(gw[0], gw[1], Wb, Wb + (size_t)F_ * F_,
                                            (F_ * F_) / 4);
  k_gemm_bf16<<<2048, 256, 0, stream>>>(xb, Wb, h);
  hipMemsetAsync(cnt, 0, (size_t)2 * N_NODES * 4, stream);
  k_hist<<<dim3(1000, 2), 256, 0, stream>>>(pro_ei[0], pro_ei[1], cnt, E_, N_NODES);
  k_scan<<<2, 256, 0, stream>>>(cnt, rowstart, cursor, dinv, N_NODES);
  k_scatter<<<dim3(1000, 2), 256, 0, stream>>>(pro_ei[0], pro_ei[1], dinv, cursor,
                                               csr, csrw, E_, N_NODES);
  // gathers sequential per graph: keeps per-XCD h working set at one 4 MB slice
  for (int g = 0; g < 2; ++g) {
    k_gather<<<dim3(8, N_NODES), 64, 0, stream>>>(
        (const ushort2*)(h + (size_t)g * N_NODES * F_), dinv + (size_t)g * N_NODES,
        rowstart + (size_t)g * (N_NODES + 1), csr + (size_t)g * E_, csrw + (size_t)g * E_,
        (ushort2*)(agg + (size_t)g * N_NODES * F_));
  }
  hipMemsetAsync(pooled, 0, (size_t)2 * B_ * F_ * 4, stream);
  k_pool<<<dim3(4, 5, 64), 256, 0, stream>>>(agg, gb[0], gb[1], pooled);
  k_fc<<<dim3(B_, 2), 128, 0, stream>>>(pooled, fcw[0], fcw[1], fcb[0], fcb[1],
                                        xg[0], xg[1]);

  // ---- ragged pack ----
  hipMemsetAsync(seq, 0, (size_t)B_ * MAXLEN_ * TD_ * 4, stream);
  k_pack<<<dim3(LSUB_, B_, 4), 64, 0, stream>>>(mas[0], mas[1], mas[2], mas[3],
                                                lens[0], lens[1], lens[2], lens[3],
                                                red_w, red_b, seq);
  k_totlen<<<1, 64, 0, stream>>>(lens[0], lens[1], lens[2], lens[3], totlen);

  // ---- transformer (2 layers) ----
  for (int li = 0; li < 2; ++li) {
    k_qkv<<<B_ * MAXLEN_, 128, 0, stream>>>(seq, attn_in_w + (size_t)li * 96 * TD_,
                                            attn_in_b + (size_t)li * 96, totlen, qkv);
    k_attn<<<dim3(NH_, B_, 8), 128, 0, stream>>>(qkv, totlen, obuf);
    k_oproj_ln<<<(B_ * MAXLEN_) / 8, 256, 0, stream>>>(
        obuf, attn_out_w + (size_t)li * TD_ * TD_, attn_out_b + (size_t)li * TD_,
        ln1_w + (size_t)li * TD_, ln1_b + (size_t)li * TD_, totlen, seq);
    k_ffn_ln<<<B_ * MAXLEN_, 128, 0, stream>>>(
        ff1_w + (size_t)li * DFF_ * TD_, ff1_b + (size_t)li * DFF_,
        ff2_w + (size_t)li * TD_ * DFF_, ff2_b + (size_t)li * TD_,
        ln2_w + (size_t)li * TD_, ln2_b + (size_t)li * TD_, totlen, seq);
  }

  // ---- masked mean + final ----
  k_maskmean<<<B_, 256, 0, stream>>>(seq, totlen, masout);
  k_final<<<B_, 64, 0, stream>>>(xg[0], xg[1], masout, final_w, final_b, out);
}

// Round 8
// 854.392 us; speedup vs baseline: 1.1115x; 1.1115x over previous
//
#include <hip/hip_runtime.h>
#include <stdint.h>

// ---- problem constants (from reference) ----
#define N_NODES 16000
#define B_      32
#define NPG_    500
#define E_      256000
#define F_      1024
#define OD_     128
#define DD_     80
#define TD_     32
#define NH_     4
#define DH_     8
#define DFF_    128
#define LSUB_   128
#define MAXLEN_ 512
#define EPS_    1e-5f
#define SLOPE_  0.01f

typedef __bf16 bf16x8 __attribute__((ext_vector_type(8)));
typedef float  f32x4  __attribute__((ext_vector_type(4)));

__device__ __forceinline__ float leaky(float v) { return v >= 0.f ? v : SLOPE_ * v; }

__device__ __forceinline__ unsigned short f2bf(float f) {
  unsigned u = __float_as_uint(f);
  u += 0x7FFFu + ((u >> 16) & 1u);   // RNE
  return (unsigned short)(u >> 16);
}
__device__ __forceinline__ float bf2f(unsigned short u) {
  return __uint_as_float((unsigned)u << 16);
}

__device__ __forceinline__ void gld_lds16(const void* g, void* l) {
  __builtin_amdgcn_global_load_lds(
      (const __attribute__((address_space(1))) unsigned int*)g,
      (__attribute__((address_space(3))) unsigned int*)l, 16, 0, 0);
}

// ---- fp32 -> bf16 conversion for two tensors (grid.y selects) ----
__global__ void k_f2bf2(const float* __restrict__ in0, const float* __restrict__ in1,
                        unsigned short* __restrict__ out0, unsigned short* __restrict__ out1,
                        int n4) {
  const float* in = blockIdx.y ? in1 : in0;
  unsigned short* out = blockIdx.y ? out1 : out0;
  int i = blockIdx.x * blockDim.x + threadIdx.x;
  int stride = gridDim.x * blockDim.x;
  for (; i < n4; i += stride) {
    float4 v = ((const float4*)in)[i];
    ushort4 o;
    o.x = f2bf(v.x); o.y = f2bf(v.y); o.z = f2bf(v.z); o.w = f2bf(v.w);
    ((ushort4*)out)[i] = o;
  }
}

// ---- bf16 MFMA GEMM: C[M,N] = A[M,K]*B[N,K]^T, bf16 out; grid (125,8,2).
// A/B results across rounds: x-fastest grid + HBM streaming (r4, 110us) beats
// XCD-swizzled L2-resident (r5/r6, 146us: low-MLP latency-bound) and
// barrier-free direct-global (r7, 243us: per-wave L2 round-trips). Here:
// round-4 grid + round-5 fragment-ordered LDS (lane-linear ds_read_b128,
// 0 bank conflicts; r4's row-major layout burned 8.2M conflict cycles).
__global__ __launch_bounds__(256) void k_gemm_bf16(const unsigned short* __restrict__ A,
                                                   const unsigned short* __restrict__ Bw,
                                                   unsigned short* __restrict__ C) {
  const int K = 1024, N = 1024;
  const size_t g = blockIdx.z;
  A  += g * (size_t)N_NODES * K;
  Bw += g * (size_t)K * N;
  C  += g * (size_t)N_NODES * N;
  const int mBase = blockIdx.x * 128;
  const int nBase = blockIdx.y * 128;

  __shared__ short As[8 * 512];   // 8 tiles of 16 rows x 32 k, fragment-ordered
  __shared__ short Bs[8 * 512];
  const int t    = threadIdx.x;
  const int lane = t & 63, wave = t >> 6;
  const int wrow = wave >> 1, wcol = wave & 1;
  const int quad = lane >> 4, l15 = lane & 15;
  const int rI = lane & 15;      // staging: row within 16-row tile
  const int cI = lane >> 4;      // staging: k-chunk (8 bf16 = 16 B)

  f32x4 acc[4][4];
  f32x4 zero = {0.f, 0.f, 0.f, 0.f};
#pragma unroll
  for (int i = 0; i < 4; ++i)
#pragma unroll
    for (int jj = 0; jj < 4; ++jj) acc[i][jj] = zero;

  const int tile0 = wave * 2, tile1 = wave * 2 + 1;
  const unsigned short* aP0 = &A[(size_t)(mBase + tile0 * 16 + rI) * K + cI * 8];
  const unsigned short* aP1 = &A[(size_t)(mBase + tile1 * 16 + rI) * K + cI * 8];
  const unsigned short* bP0 = &Bw[(size_t)(nBase + tile0 * 16 + rI) * K + cI * 8];
  const unsigned short* bP1 = &Bw[(size_t)(nBase + tile1 * 16 + rI) * K + cI * 8];

  for (int kt = 0; kt < 32; ++kt) {
    const int k0 = kt * 32;
    gld_lds16(aP0 + k0, &As[tile0 * 512 + lane * 8]);
    gld_lds16(aP1 + k0, &As[tile1 * 512 + lane * 8]);
    gld_lds16(bP0 + k0, &Bs[tile0 * 512 + lane * 8]);
    gld_lds16(bP1 + k0, &Bs[tile1 * 512 + lane * 8]);
    __syncthreads();

    bf16x8 a[4], b[4];
#pragma unroll
    for (int ti = 0; ti < 4; ++ti)
      a[ti] = *(const bf16x8*)&As[(wrow * 4 + ti) * 512 + lane * 8];
#pragma unroll
    for (int tj = 0; tj < 4; ++tj)
      b[tj] = *(const bf16x8*)&Bs[(wcol * 4 + tj) * 512 + lane * 8];
#pragma unroll
    for (int ti = 0; ti < 4; ++ti)
#pragma unroll
      for (int tj = 0; tj < 4; ++tj)
        acc[ti][tj] = __builtin_amdgcn_mfma_f32_16x16x32_bf16(a[ti], b[tj], acc[ti][tj], 0, 0, 0);
    __syncthreads();
  }

#pragma unroll
  for (int ti = 0; ti < 4; ++ti)
#pragma unroll
    for (int tj = 0; tj < 4; ++tj)
#pragma unroll
      for (int r = 0; r < 4; ++r) {
        int grow = mBase + wrow * 64 + ti * 16 + quad * 4 + r;
        int gcol = nBase + wcol * 64 + tj * 16 + l15;
        C[(size_t)grow * N + gcol] = f2bf(acc[ti][tj][r]);
      }
}

// ---- degree histogram over dst (grid.y = graph) ----
__global__ void k_hist(const int* __restrict__ ei0, const int* __restrict__ ei1,
                       int* __restrict__ cnt, int e, int n) {
  const int g = blockIdx.y;
  const int* dst = (g ? ei1 : ei0) + e;
  int i = blockIdx.x * 256 + threadIdx.x;
  if (i < e) atomicAdd(&cnt[g * n + dst[i]], 1);
}

// ---- per-graph block: exclusive scan of cnt -> rowstart/cursor; dinv = rsqrt(cnt+1) ----
__global__ void k_scan(const int* __restrict__ cnt_all, int* __restrict__ rowstart_all,
                       int* __restrict__ cursor_all, float* __restrict__ dinv_all, int n) {
  const int g = blockIdx.x;
  const int* cnt = cnt_all + g * n;
  int* rowstart = rowstart_all + g * (n + 1);
  int* cursor   = cursor_all + g * n;
  float* dinv   = dinv_all + g * n;
  __shared__ int part[256];
  __shared__ int base[257];
  int t = threadIdx.x;
  int chunk = (n + 255) >> 8;
  int s = 0;
  for (int j = 0; j < chunk; ++j) {
    int idx = t * chunk + j;
    if (idx < n) s += cnt[idx];
  }
  part[t] = s;
  __syncthreads();
  if (t == 0) {
    int a = 0;
    for (int i = 0; i < 256; ++i) { base[i] = a; a += part[i]; }
    base[256] = a;
  }
  __syncthreads();
  int a = base[t];
  for (int j = 0; j < chunk; ++j) {
    int idx = t * chunk + j;
    if (idx < n) {
      int c = cnt[idx];
      rowstart[idx] = a; cursor[idx] = a; a += c;
      dinv[idx] = rsqrtf((float)c + 1.0f);
    }
  }
  if (t == 0) rowstart[n] = base[256];
}

// ---- scatter edges to CSR, precomputing edge weight dinv[s]*dinv[d] (grid.y = graph) ----
__global__ void k_scatter(const int* __restrict__ ei0, const int* __restrict__ ei1,
                          const float* __restrict__ dinv_all, int* __restrict__ cursor_all,
                          int* __restrict__ csr_all, float* __restrict__ csrw_all,
                          int e, int n) {
  const int g = blockIdx.y;
  const int* ei = g ? ei1 : ei0;
  int i = blockIdx.x * 256 + threadIdx.x;
  if (i < e) {
    int s = ei[i], d = ei[e + i];
    int p = atomicAdd(&cursor_all[g * n + d], 1);
    csr_all[(size_t)g * e + p]  = s;
    csrw_all[(size_t)g * e + p] = dinv_all[g * n + s] * dinv_all[g * n + d];
  }
}

// ---- sliced CSR gather: grid (8 slices, 16000 dst). slice == linear%8 -> stable XCD
//      under round-robin dispatch => per-XCD h working set = 4 MB (L2-resident). ----
__global__ __launch_bounds__(64) void k_gather(const ushort2* __restrict__ h2,
                                               const float* __restrict__ dinv,
                                               const int* __restrict__ rowstart,
                                               const int* __restrict__ csr,
                                               const float* __restrict__ csrw,
                                               ushort2* __restrict__ agg2) {
  const int sl = blockIdx.x;   // 0..7 feature slice (128 features = 64 ushort2)
  const int i  = blockIdx.y;   // dst node
  const int t  = threadIdx.x;  // 64
  __shared__ int   ssrc[64];
  __shared__ float sw[64];
  const float di = dinv[i];
  const size_t fo = (size_t)sl * 64 + t;
  ushort2 sv = h2[(size_t)i * 512 + fo];
  const float selfw = di * di;
  float ax = bf2f(sv.x) * selfw, ay = bf2f(sv.y) * selfw;
  const int beg = rowstart[i], end = rowstart[i + 1];
  for (int base = beg; base < end; base += 64) {
    int c = end - base; if (c > 64) c = 64;
    __syncthreads();
    if (t < c) { ssrc[t] = csr[base + t]; sw[t] = csrw[base + t]; }
    __syncthreads();
    int j = 0;
    for (; j + 4 <= c; j += 4) {
      ushort2 v0 = h2[(size_t)ssrc[j]     * 512 + fo];
      ushort2 v1 = h2[(size_t)ssrc[j + 1] * 512 + fo];
      ushort2 v2 = h2[(size_t)ssrc[j + 2] * 512 + fo];
      ushort2 v3 = h2[(size_t)ssrc[j + 3] * 512 + fo];
      float w0 = sw[j], w1 = sw[j + 1], w2 = sw[j + 2], w3 = sw[j + 3];
      ax += bf2f(v0.x) * w0 + bf2f(v1.x) * w1 + bf2f(v2.x) * w2 + bf2f(v3.x) * w3;
      ay += bf2f(v0.y) * w0 + bf2f(v1.y) * w1 + bf2f(v2.y) * w2 + bf2f(v3.y) * w3;
    }
    for (; j < c; ++j) {
      ushort2 v0 = h2[(size_t)ssrc[j] * 512 + fo];
      float w0 = sw[j];
      ax += bf2f(v0.x) * w0; ay += bf2f(v0.y) * w0;
    }
  }
  ushort2 o; o.x = f2bf(ax); o.y = f2bf(ay);
  agg2[(size_t)i * 512 + fo] = o;
}

// ---- mean pool of leaky(agg + bias); grid.z in [0,64): g = z>>5, b = z&31 ----
__global__ void k_pool(const unsigned short* __restrict__ agg_all,
                       const float* __restrict__ bias0, const float* __restrict__ bias1,
                       float* __restrict__ pooled_all) {
  int f = blockIdx.x * 256 + threadIdx.x;  // 0..1023
  int z = blockIdx.z;
  int g = z >> 5, b = z & 31;
  const unsigned short* agg = agg_all + (size_t)g * N_NODES * F_;
  const float* bias = g ? bias1 : bias0;
  float* pooled = pooled_all + (size_t)g * B_ * F_;
  int r0 = blockIdx.y * 100;
  float bf = bias[f];
  float s = 0.f;
  for (int r = 0; r < 100; ++r)
    s += leaky(bf2f(agg[(size_t)(b * NPG_ + r0 + r) * F_ + f]) + bf);
  atomicAdd(&pooled[b * F_ + f], s);
}

// ---- fc (grid.y = graph) ----
__global__ void k_fc(const float* __restrict__ pooled_all,
                     const float* __restrict__ w0, const float* __restrict__ w1,
                     const float* __restrict__ bias0, const float* __restrict__ bias1,
                     float* __restrict__ out0, float* __restrict__ out1) {
  int b = blockIdx.x, o = threadIdx.x, g = blockIdx.y;
  const float* p  = pooled_all + (size_t)g * B_ * F_ + b * F_;
  const float* wr = (g ? w1 : w0) + o * F_;
  const float* bias = g ? bias1 : bias0;
  float* out = g ? out1 : out0;
  float acc = 0.f;
  for (int f = 0; f < F_; ++f) acc += p[f] * wr[f];
  out[b * OD_ + o] = leaky(acc * (1.f / 500.f) + bias[o]);
}

// ---- ragged pack ----
__global__ void k_pack(const float* __restrict__ m0, const float* __restrict__ m1,
                       const float* __restrict__ m2, const float* __restrict__ m3,
                       const int* __restrict__ l0, const int* __restrict__ l1,
                       const int* __restrict__ l2, const int* __restrict__ l3,
                       const float* __restrict__ rw, const float* __restrict__ rb,
                       float* __restrict__ seq) {
  __shared__ float xs[DD_];
  const int p = blockIdx.x, b = blockIdx.y, k = blockIdx.z;
  const float* mas = (k == 0) ? m0 : (k == 1) ? m1 : (k == 2) ? m2 : m3;
  const int*   lk  = (k == 0) ? l0 : (k == 1) ? l1 : (k == 2) ? l2 : l3;
  const int len = lk[b];
  if (p >= len) return;
  int off = 0;
  if (k > 0) off += l0[b];
  if (k > 1) off += l1[b];
  if (k > 2) off += l2[b];
  const int t = threadIdx.x;  // 64
  for (int d = t; d < DD_; d += 64) xs[d] = mas[(size_t)(b * LSUB_ + p) * DD_ + d];
  __syncthreads();
  if (t < TD_) {
    float v;
    if (t < TD_ - 2) {
      float a = rb[t];
      const float* w = &rw[t * DD_];
      for (int d = 0; d < DD_; ++d) a += xs[d] * w[d];
      v = a;
    } else if (t == TD_ - 2) {
      v = (k == 0 || k == 2) ? 1.f : 0.f;
    } else {
      v = (k < 2) ? 1.f : 0.f;
    }
    seq[((size_t)b * MAXLEN_ + off + p) * TD_ + t] = v;
  }
}

__global__ void k_totlen(const int* __restrict__ l0, const int* __restrict__ l1,
                         const int* __restrict__ l2, const int* __restrict__ l3,
                         int* __restrict__ tot) {
  int b = threadIdx.x;
  if (b < B_) tot[b] = l0[b] + l1[b] + l2[b] + l3[b];
}

// ---- qkv projection (skip dead rows) ----
__global__ void k_qkv(const float* __restrict__ xt, const float* __restrict__ w,
                      const float* __restrict__ bias, const int* __restrict__ tot,
                      float* __restrict__ qkv) {
  __shared__ float xs[TD_];
  const int row = blockIdx.x;
  if ((row & (MAXLEN_ - 1)) >= tot[row >> 9]) return;
  const int t = threadIdx.x;      // 128
  if (t < TD_) xs[t] = xt[(size_t)row * TD_ + t];
  __syncthreads();
  if (t < 3 * TD_) {
    float a = bias[t];
    const float* wr = &w[t * TD_];
#pragma unroll
    for (int k = 0; k < TD_; ++k) a += xs[k] * wr[k];
    qkv[(size_t)row * 96 + t] = a;
  }
}

// ---- attention: one lane-pair per query, single pass (scores |s|<~1) ----
__global__ __launch_bounds__(128) void k_attn(const float* __restrict__ qkv,
                                              const int* __restrict__ tot,
                                              float* __restrict__ obuf) {
  __shared__ float Kl[MAXLEN_ * DH_];
  __shared__ float Vl[MAXLEN_ * DH_];
  const int h = blockIdx.x, b = blockIdx.y, qz = blockIdx.z;
  const int t = threadIdx.x;  // 128
  const int L = tot[b];
  if (qz * 64 >= L) return;
  const float* base = &qkv[(size_t)b * MAXLEN_ * 96];
  for (int i = t; i < L * DH_; i += 128) {
    int p = i >> 3, d = i & 7;
    Kl[i] = base[p * 96 + 32 + h * 8 + d];
    Vl[i] = base[p * 96 + 64 + h * 8 + d];
  }
  __syncthreads();
  const int qi = qz * 64 + (t >> 1);
  if (qi >= L) return;
  const int half = t & 1;
  const float scale = 0.35355339059327373f;  // 1/sqrt(8)
  float q[8];
#pragma unroll
  for (int d = 0; d < 8; ++d) q[d] = base[qi * 96 + h * 8 + d] * scale;

  float l0 = 0.f, l1 = 0.f;
  float a0[8] = {0, 0, 0, 0, 0, 0, 0, 0};
  float a1[8] = {0, 0, 0, 0, 0, 0, 0, 0};
  int j = half;
  for (; j + 2 < L; j += 4) {
    const float* kr0 = &Kl[j * 8];
    const float* kr1 = &Kl[(j + 2) * 8];
    float s0 = 0.f, s1 = 0.f;
#pragma unroll
    for (int d = 0; d < 8; ++d) { s0 += q[d] * kr0[d]; s1 += q[d] * kr1[d]; }
    float p0 = __expf(s0), p1 = __expf(s1);
    l0 += p0; l1 += p1;
    const float* vr0 = &Vl[j * 8];
    const float* vr1 = &Vl[(j + 2) * 8];
#pragma unroll
    for (int d = 0; d < 8; ++d) { a0[d] += p0 * vr0[d]; a1[d] += p1 * vr1[d]; }
  }
  for (; j < L; j += 2) {
    const float* kr = &Kl[j * 8];
    float s = 0.f;
#pragma unroll
    for (int d = 0; d < 8; ++d) s += q[d] * kr[d];
    float p = __expf(s);
    l0 += p;
    const float* vr = &Vl[j * 8];
#pragma unroll
    for (int d = 0; d < 8; ++d) a0[d] += p * vr[d];
  }
  float l = l0 + l1;
#pragma unroll
  for (int d = 0; d < 8; ++d) a0[d] += a1[d];
  l += __shfl_xor(l, 1);
#pragma unroll
  for (int d = 0; d < 8; ++d) a0[d] += __shfl_xor(a0[d], 1);
  float inv = 1.f / l;
  const int dbase = half * 4;
  float4 o;
  o.x = a0[dbase + 0] * inv; o.y = a0[dbase + 1] * inv;
  o.z = a0[dbase + 2] * inv; o.w = a0[dbase + 3] * inv;
  *(float4*)&obuf[((size_t)b * MAXLEN_ + qi) * TD_ + h * 8 + dbase] = o;
}

// ---- out-proj + residual + LN1 (skip dead rows) ----
__global__ void k_oproj_ln(const float* __restrict__ obuf, const float* __restrict__ w,
                           const float* __restrict__ bias, const float* __restrict__ lw,
                           const float* __restrict__ lb, const int* __restrict__ tot,
                           float* __restrict__ xt) {
  const int t = threadIdx.x;             // 256
  const int r = blockIdx.x * 8 + (t >> 5);
  if ((r & (MAXLEN_ - 1)) >= tot[r >> 9]) return;
  const int j = t & 31;
  const float* orow = &obuf[(size_t)r * TD_];
  float a = bias[j] + xt[(size_t)r * TD_ + j];
  const float* wr = &w[j * TD_];
#pragma unroll
  for (int k = 0; k < TD_; ++k) a += orow[k] * wr[k];
  float s1 = a, s2 = a * a;
#pragma unroll
  for (int m = 1; m < 32; m <<= 1) {
    s1 += __shfl_xor(s1, m, 32);
    s2 += __shfl_xor(s2, m, 32);
  }
  float mean = s1 * (1.f / 32.f);
  float var  = s2 * (1.f / 32.f) - mean * mean;
  xt[(size_t)r * TD_ + j] = (a - mean) * rsqrtf(var + EPS_) * lw[j] + lb[j];
}

// ---- FFN (relu) + residual + LN2 (skip dead rows) ----
__global__ void k_ffn_ln(const float* __restrict__ w1, const float* __restrict__ b1,
                         const float* __restrict__ w2, const float* __restrict__ b2,
                         const float* __restrict__ lw, const float* __restrict__ lb,
                         const int* __restrict__ tot, float* __restrict__ xt) {
  const int r = blockIdx.x, t = threadIdx.x;  // 128
  if ((r & (MAXLEN_ - 1)) >= tot[r >> 9]) return;
  __shared__ float xs[TD_];
  __shared__ float hb[DFF_];
  if (t < TD_) xs[t] = xt[(size_t)r * TD_ + t];
  __syncthreads();
  {
    float a = b1[t];
    const float* wr = &w1[t * TD_];
#pragma unroll
    for (int k = 0; k < TD_; ++k) a += xs[k] * wr[k];
    hb[t] = fmaxf(a, 0.f);
  }
  __syncthreads();
  if (t < TD_) {
    float a = b2[t] + xs[t];
    const float* wr = &w2[t * DFF_];
#pragma unroll
    for (int k = 0; k < DFF_; ++k) a += hb[k] * wr[k];
    float s1 = a, s2 = a * a;
#pragma unroll
    for (int m = 1; m < 32; m <<= 1) {
      s1 += __shfl_xor(s1, m, 32);
      s2 += __shfl_xor(s2, m, 32);
    }
    float mean = s1 * (1.f / 32.f);
    float var  = s2 * (1.f / 32.f) - mean * mean;
    xt[(size_t)r * TD_ + t] = (a - mean) * rsqrtf(var + EPS_) * lw[t] + lb[t];
  }
}

// ---- masked mean ----
__global__ void k_maskmean(const float* __restrict__ xt, const int* __restrict__ tot,
                           float* __restrict__ mout) {
  __shared__ float sbuf[8][32];
  const int b = blockIdx.x, t = threadIdx.x;  // 256
  const int j = t & 31, c = t >> 5;
  const int L = tot[b];
  float s = 0.f;
  for (int p = c; p < L; p += 8) s += xt[((size_t)b * MAXLEN_ + p) * TD_ + j];
  sbuf[c][j] = s;
  __syncthreads();
  if (t < 32) {
    float a = 0.f;
#pragma unroll
    for (int cc = 0; cc < 8; ++cc) a += sbuf[cc][t];
    mout[b * TD_ + t] = a / (float)L;
  }
}

// ---- final linear ----
__global__ void k_final(const float* __restrict__ x1, const float* __restrict__ x2,
                        const float* __restrict__ mo, const float* __restrict__ fw,
                        const float* __restrict__ fb, float* __restrict__ out) {
  const int b = blockIdx.x, t = threadIdx.x;  // 64
  float s = 0.f;
  for (int i = t; i < 2 * OD_ + TD_; i += 64) {
    float c = (i < OD_) ? x1[b * OD_ + i]
            : (i < 2 * OD_) ? x2[b * OD_ + (i - OD_)]
            : mo[b * TD_ + (i - 2 * OD_)];
    s += fw[i] * c;
  }
#pragma unroll
  for (int m = 1; m < 64; m <<= 1) s += __shfl_xor(s, m, 64);
  if (t == 0) out[b] = s + fb[0];
}

extern "C" void kernel_launch(void* const* d_in, const int* in_sizes, int n_in,
                              void* d_out, int out_size, void* d_ws, size_t ws_size,
                              hipStream_t stream) {
  (void)in_sizes; (void)n_in; (void)out_size; (void)ws_size;
  const float* pro_x[2]  = {(const float*)d_in[0], (const float*)d_in[1]};
  const int*   pro_ei[2] = {(const int*)d_in[2], (const int*)d_in[3]};
  const float* mas[4]    = {(const float*)d_in[6], (const float*)d_in[8],
                            (const float*)d_in[10], (const float*)d_in[12]};
  const int*   lens[4]   = {(const int*)d_in[7], (const int*)d_in[9],
                            (const int*)d_in[11], (const int*)d_in[13]};
  const float* gw[2]  = {(const float*)d_in[14], (const float*)d_in[16]};
  const float* gb[2]  = {(const float*)d_in[15], (const float*)d_in[17]};
  const float* fcw[2] = {(const float*)d_in[18], (const float*)d_in[20]};
  const float* fcb[2] = {(const float*)d_in[19], (const float*)d_in[21]};
  const float* red_w = (const float*)d_in[22];
  const float* red_b = (const float*)d_in[23];
  const float* attn_in_w  = (const float*)d_in[24];
  const float* attn_in_b  = (const float*)d_in[25];
  const float* attn_out_w = (const float*)d_in[26];
  const float* attn_out_b = (const float*)d_in[27];
  const float* ln1_w = (const float*)d_in[28];
  const float* ln1_b = (const float*)d_in[29];
  const float* ln2_w = (const float*)d_in[30];
  const float* ln2_b = (const float*)d_in[31];
  const float* ff1_w = (const float*)d_in[32];
  const float* ff1_b = (const float*)d_in[33];
  const float* ff2_w = (const float*)d_in[34];
  const float* ff2_b = (const float*)d_in[35];
  const float* final_w = (const float*)d_in[36];
  const float* final_b = (const float*)d_in[37];
  float* out = (float*)d_out;

  char* p = (char*)d_ws;
  auto carve = [&](size_t bytes) -> void* {
    void* r = (void*)p;
    p += (bytes + 255) & ~(size_t)255;
    return r;
  };
  unsigned short* xb  = (unsigned short*)carve((size_t)2 * N_NODES * F_ * 2);
  unsigned short* Wb  = (unsigned short*)carve((size_t)2 * F_ * F_ * 2);
  unsigned short* h   = (unsigned short*)carve((size_t)2 * N_NODES * F_ * 2);
  unsigned short* agg = (unsigned short*)carve((size_t)2 * N_NODES * F_ * 2);
  int*   cnt      = (int*)carve((size_t)2 * N_NODES * 4);
  float* dinv     = (float*)carve((size_t)2 * N_NODES * 4);
  int*   rowstart = (int*)carve((size_t)2 * (N_NODES + 1) * 4);
  int*   cursor   = (int*)carve((size_t)2 * N_NODES * 4);
  int*   csr      = (int*)carve((size_t)2 * E_ * 4);
  float* csrw     = (float*)carve((size_t)2 * E_ * 4);
  float* pooled   = (float*)carve((size_t)2 * B_ * F_ * 4);
  float* xg[2];
  xg[0] = (float*)carve((size_t)B_ * OD_ * 4);
  xg[1] = (float*)carve((size_t)B_ * OD_ * 4);
  float* seq    = (float*)carve((size_t)B_ * MAXLEN_ * TD_ * 4);
  float* qkv    = (float*)carve((size_t)B_ * MAXLEN_ * 96 * 4);
  float* obuf   = (float*)carve((size_t)B_ * MAXLEN_ * TD_ * 4);
  int*   totlen = (int*)carve((size_t)B_ * 4);
  float* masout = (float*)carve((size_t)B_ * TD_ * 4);

  // ---- GCN branches (merged across both graphs) ----
  k_f2bf2<<<dim3(1024, 2), 256, 0, stream>>>(pro_x[0], pro_x[1], xb,
                                             xb + (size_t)N_NODES * F_, (N_NODES * F_) / 4);
  k_f2bf2<<<dim3(512, 2), 256, 0, stream>>>(gw[0], gw[1], Wb, Wb + (size_t)F_ * F_,
                                            (F_ * F_) / 4);
  k_gemm_bf16<<<dim3(125, 8, 2), 256, 0, stream>>>(xb, Wb, h);
  hipMemsetAsync(cnt, 0, (size_t)2 * N_NODES * 4, stream);
  k_hist<<<dim3(1000, 2), 256, 0, stream>>>(pro_ei[0], pro_ei[1], cnt, E_, N_NODES);
  k_scan<<<2, 256, 0, stream>>>(cnt, rowstart, cursor, dinv, N_NODES);
  k_scatter<<<dim3(1000, 2), 256, 0, stream>>>(pro_ei[0], pro_ei[1], dinv, cursor,
                                               csr, csrw, E_, N_NODES);
  // gathers sequential per graph: keeps per-XCD h working set at one 4 MB slice
  for (int g = 0; g < 2; ++g) {
    k_gather<<<dim3(8, N_NODES), 64, 0, stream>>>(
        (const ushort2*)(h + (size_t)g * N_NODES * F_), dinv + (size_t)g * N_NODES,
        rowstart + (size_t)g * (N_NODES + 1), csr + (size_t)g * E_, csrw + (size_t)g * E_,
        (ushort2*)(agg + (size_t)g * N_NODES * F_));
  }
  hipMemsetAsync(pooled, 0, (size_t)2 * B_ * F_ * 4, stream);
  k_pool<<<dim3(4, 5, 64), 256, 0, stream>>>(agg, gb[0], gb[1], pooled);
  k_fc<<<dim3(B_, 2), 128, 0, stream>>>(pooled, fcw[0], fcw[1], fcb[0], fcb[1],
                                        xg[0], xg[1]);

  // ---- ragged pack ----
  hipMemsetAsync(seq, 0, (size_t)B_ * MAXLEN_ * TD_ * 4, stream);
  k_pack<<<dim3(LSUB_, B_, 4), 64, 0, stream>>>(mas[0], mas[1], mas[2], mas[3],
                                                lens[0], lens[1], lens[2], lens[3],
                                                red_w, red_b, seq);
  k_totlen<<<1, 64, 0, stream>>>(lens[0], lens[1], lens[2], lens[3], totlen);

  // ---- transformer (2 layers) ----
  for (int li = 0; li < 2; ++li) {
    k_qkv<<<B_ * MAXLEN_, 128, 0, stream>>>(seq, attn_in_w + (size_t)li * 96 * TD_,
                                            attn_in_b + (size_t)li * 96, totlen, qkv);
    k_attn<<<dim3(NH_, B_, 8), 128, 0, stream>>>(qkv, totlen, obuf);
    k_oproj_ln<<<(B_ * MAXLEN_) / 8, 256, 0, stream>>>(
        obuf, attn_out_w + (size_t)li * TD_ * TD_, attn_out_b + (size_t)li * TD_,
        ln1_w + (size_t)li * TD_, ln1_b + (size_t)li * TD_, totlen, seq);
    k_ffn_ln<<<B_ * MAXLEN_, 128, 0, stream>>>(
        ff1_w + (size_t)li * DFF_ * TD_, ff1_b + (size_t)li * DFF_,
        ff2_w + (size_t)li * TD_ * DFF_, ff2_b + (size_t)li * TD_,
        ln2_w + (size_t)li * TD_, ln2_b + (size_t)li * TD_, totlen, seq);
  }

  // ---- masked mean + final ----
  k_maskmean<<<B_, 256, 0, stream>>>(seq, totlen, masout);
  k_final<<<B_, 64, 0, stream>>>(xg[0], xg[1], masout, final_w, final_b, out);
}

// Round 9
// 813.414 us; speedup vs baseline: 1.1675x; 1.0504x over previous
//
#include <hip/hip_runtime.h>
#include <stdint.h>

// ---- problem constants (from reference) ----
#define N_NODES 16000
#define B_      32
#define NPG_    500
#define E_      256000
#define F_      1024
#define OD_     128
#define DD_     80
#define TD_     32
#define NH_     4
#define DH_     8
#define DFF_    128
#define LSUB_   128
#define MAXLEN_ 512
#define EPS_    1e-5f
#define SLOPE_  0.01f

typedef __bf16 bf16x8 __attribute__((ext_vector_type(8)));
typedef float  f32x4  __attribute__((ext_vector_type(4)));

__device__ __forceinline__ float leaky(float v) { return v >= 0.f ? v : SLOPE_ * v; }

__device__ __forceinline__ unsigned short f2bf(float f) {
  unsigned u = __float_as_uint(f);
  u += 0x7FFFu + ((u >> 16) & 1u);   // RNE
  return (unsigned short)(u >> 16);
}
__device__ __forceinline__ float bf2f(unsigned short u) {
  return __uint_as_float((unsigned)u << 16);
}

__device__ __forceinline__ void gld_lds16(const void* g, void* l) {
  __builtin_amdgcn_global_load_lds(
      (const __attribute__((address_space(1))) unsigned int*)g,
      (__attribute__((address_space(3))) unsigned int*)l, 16, 0, 0);
}

// ---- fp32 -> bf16 conversion for two tensors (grid.y selects) ----
__global__ void k_f2bf2(const float* __restrict__ in0, const float* __restrict__ in1,
                        unsigned short* __restrict__ out0, unsigned short* __restrict__ out1,
                        int n4) {
  const float* in = blockIdx.y ? in1 : in0;
  unsigned short* out = blockIdx.y ? out1 : out0;
  int i = blockIdx.x * blockDim.x + threadIdx.x;
  int stride = gridDim.x * blockDim.x;
  for (; i < n4; i += stride) {
    float4 v = ((const float4*)in)[i];
    ushort4 o;
    o.x = f2bf(v.x); o.y = f2bf(v.y); o.z = f2bf(v.z); o.w = f2bf(v.w);
    ((ushort4*)out)[i] = o;
  }
}

// ---- bf16 MFMA GEMM: C[M,N] = A[M,K]*B[N,K]^T, bf16 out; grid (125,8,2).
// Round-4 structure (x-fast grid + HBM streaming + lane-contiguous 64B
// staging = 3.2 TB/s, the A/B winner across r4-r8) with ONE change: a
// chunk-slot swizzle, slot = (chunk + (row>>1)) & 3. Staging coalescing is
// unchanged (4 lanes still cover one 64B row segment, chunks permuted
// within); MFMA ds_read_b128 becomes phase-ordered — consecutive 8 lanes
// cover all 32 banks exactly once (r4's row-major order had lane0/lane2
// both on banks 0-3 -> 8.2M conflict cycles, ~12% of the kernel).
__global__ __launch_bounds__(256) void k_gemm_bf16(const unsigned short* __restrict__ A,
                                                   const unsigned short* __restrict__ Bw,
                                                   unsigned short* __restrict__ C) {
  const int K = 1024, N = 1024;
  const size_t g = blockIdx.z;
  A  += g * (size_t)N_NODES * K;
  Bw += g * (size_t)K * N;
  C  += g * (size_t)N_NODES * N;
  __shared__ short As[128 * 32];
  __shared__ short Bs[128 * 32];
  const int t    = threadIdx.x;
  const int lane = t & 63, wave = t >> 6;
  const int wrow = wave >> 1, wcol = wave & 1;
  const int quad = lane >> 4, l15 = lane & 15;
  const int mBase = blockIdx.x * 128;
  const int nBase = blockIdx.y * 128;

  f32x4 acc[4][4];
  f32x4 zero = {0.f, 0.f, 0.f, 0.f};
#pragma unroll
  for (int i = 0; i < 4; ++i)
#pragma unroll
    for (int j = 0; j < 4; ++j) acc[i][j] = zero;

  const int r4 = t >> 2;                            // 0..63 : row within half-tile
  const int c4 = (((t & 3) - ((t >> 3) & 3)) & 3) * 8;  // swizzled chunk -> bf16 k-offset
  const int rs = ((quad + (l15 >> 1)) & 3) * 8;     // read-side swizzled slot (shorts)

  for (int kt = 0; kt < 32; ++kt) {
    const int k0 = kt * 32;
    gld_lds16(&A[(size_t)(mBase + r4) * K + k0 + c4],       &As[t * 8]);
    gld_lds16(&A[(size_t)(mBase + 64 + r4) * K + k0 + c4],  &As[2048 + t * 8]);
    gld_lds16(&Bw[(size_t)(nBase + r4) * K + k0 + c4],      &Bs[t * 8]);
    gld_lds16(&Bw[(size_t)(nBase + 64 + r4) * K + k0 + c4], &Bs[2048 + t * 8]);
    __syncthreads();

    bf16x8 a[4], b[4];
#pragma unroll
    for (int ti = 0; ti < 4; ++ti)
      a[ti] = *(const bf16x8*)&As[(wrow * 64 + ti * 16 + l15) * 32 + rs];
#pragma unroll
    for (int tj = 0; tj < 4; ++tj)
      b[tj] = *(const bf16x8*)&Bs[(wcol * 64 + tj * 16 + l15) * 32 + rs];
#pragma unroll
    for (int ti = 0; ti < 4; ++ti)
#pragma unroll
      for (int tj = 0; tj < 4; ++tj)
        acc[ti][tj] = __builtin_amdgcn_mfma_f32_16x16x32_bf16(a[ti], b[tj], acc[ti][tj], 0, 0, 0);
    __syncthreads();
  }

#pragma unroll
  for (int ti = 0; ti < 4; ++ti)
#pragma unroll
    for (int tj = 0; tj < 4; ++tj)
#pragma unroll
      for (int r = 0; r < 4; ++r) {
        int grow = mBase + wrow * 64 + ti * 16 + quad * 4 + r;
        int gcol = nBase + wcol * 64 + tj * 16 + l15;
        C[(size_t)grow * N + gcol] = f2bf(acc[ti][tj][r]);
      }
}

// ---- degree histogram over dst (grid.y = graph) ----
__global__ void k_hist(const int* __restrict__ ei0, const int* __restrict__ ei1,
                       int* __restrict__ cnt, int e, int n) {
  const int g = blockIdx.y;
  const int* dst = (g ? ei1 : ei0) + e;
  int i = blockIdx.x * 256 + threadIdx.x;
  if (i < e) atomicAdd(&cnt[g * n + dst[i]], 1);
}

// ---- per-graph block: exclusive scan of cnt -> rowstart/cursor; dinv = rsqrt(cnt+1) ----
__global__ void k_scan(const int* __restrict__ cnt_all, int* __restrict__ rowstart_all,
                       int* __restrict__ cursor_all, float* __restrict__ dinv_all, int n) {
  const int g = blockIdx.x;
  const int* cnt = cnt_all + g * n;
  int* rowstart = rowstart_all + g * (n + 1);
  int* cursor   = cursor_all + g * n;
  float* dinv   = dinv_all + g * n;
  __shared__ int part[256];
  __shared__ int base[257];
  int t = threadIdx.x;
  int chunk = (n + 255) >> 8;
  int s = 0;
  for (int j = 0; j < chunk; ++j) {
    int idx = t * chunk + j;
    if (idx < n) s += cnt[idx];
  }
  part[t] = s;
  __syncthreads();
  if (t == 0) {
    int a = 0;
    for (int i = 0; i < 256; ++i) { base[i] = a; a += part[i]; }
    base[256] = a;
  }
  __syncthreads();
  int a = base[t];
  for (int j = 0; j < chunk; ++j) {
    int idx = t * chunk + j;
    if (idx < n) {
      int c = cnt[idx];
      rowstart[idx] = a; cursor[idx] = a; a += c;
      dinv[idx] = rsqrtf((float)c + 1.0f);
    }
  }
  if (t == 0) rowstart[n] = base[256];
}

// ---- scatter edges to CSR, precomputing edge weight dinv[s]*dinv[d] (grid.y = graph) ----
__global__ void k_scatter(const int* __restrict__ ei0, const int* __restrict__ ei1,
                          const float* __restrict__ dinv_all, int* __restrict__ cursor_all,
                          int* __restrict__ csr_all, float* __restrict__ csrw_all,
                          int e, int n) {
  const int g = blockIdx.y;
  const int* ei = g ? ei1 : ei0;
  int i = blockIdx.x * 256 + threadIdx.x;
  if (i < e) {
    int s = ei[i], d = ei[e + i];
    int p = atomicAdd(&cursor_all[g * n + d], 1);
    csr_all[(size_t)g * e + p]  = s;
    csrw_all[(size_t)g * e + p] = dinv_all[g * n + s] * dinv_all[g * n + d];
  }
}

// ---- sliced CSR gather: grid (8 slices, 16000 dst). slice == linear%8 -> stable XCD
//      under round-robin dispatch => per-XCD h working set = 4 MB (L2-resident). ----
__global__ __launch_bounds__(64) void k_gather(const ushort2* __restrict__ h2,
                                               const float* __restrict__ dinv,
                                               const int* __restrict__ rowstart,
                                               const int* __restrict__ csr,
                                               const float* __restrict__ csrw,
                                               ushort2* __restrict__ agg2) {
  const int sl = blockIdx.x;   // 0..7 feature slice (128 features = 64 ushort2)
  const int i  = blockIdx.y;   // dst node
  const int t  = threadIdx.x;  // 64
  __shared__ int   ssrc[64];
  __shared__ float sw[64];
  const float di = dinv[i];
  const size_t fo = (size_t)sl * 64 + t;
  ushort2 sv = h2[(size_t)i * 512 + fo];
  const float selfw = di * di;
  float ax = bf2f(sv.x) * selfw, ay = bf2f(sv.y) * selfw;
  const int beg = rowstart[i], end = rowstart[i + 1];
  for (int base = beg; base < end; base += 64) {
    int c = end - base; if (c > 64) c = 64;
    __syncthreads();
    if (t < c) { ssrc[t] = csr[base + t]; sw[t] = csrw[base + t]; }
    __syncthreads();
    int j = 0;
    for (; j + 4 <= c; j += 4) {
      ushort2 v0 = h2[(size_t)ssrc[j]     * 512 + fo];
      ushort2 v1 = h2[(size_t)ssrc[j + 1] * 512 + fo];
      ushort2 v2 = h2[(size_t)ssrc[j + 2] * 512 + fo];
      ushort2 v3 = h2[(size_t)ssrc[j + 3] * 512 + fo];
      float w0 = sw[j], w1 = sw[j + 1], w2 = sw[j + 2], w3 = sw[j + 3];
      ax += bf2f(v0.x) * w0 + bf2f(v1.x) * w1 + bf2f(v2.x) * w2 + bf2f(v3.x) * w3;
      ay += bf2f(v0.y) * w0 + bf2f(v1.y) * w1 + bf2f(v2.y) * w2 + bf2f(v3.y) * w3;
    }
    for (; j < c; ++j) {
      ushort2 v0 = h2[(size_t)ssrc[j] * 512 + fo];
      float w0 = sw[j];
      ax += bf2f(v0.x) * w0; ay += bf2f(v0.y) * w0;
    }
  }
  ushort2 o; o.x = f2bf(ax); o.y = f2bf(ay);
  agg2[(size_t)i * 512 + fo] = o;
}

// ---- mean pool of leaky(agg + bias); grid.z in [0,64): g = z>>5, b = z&31 ----
__global__ void k_pool(const unsigned short* __restrict__ agg_all,
                       const float* __restrict__ bias0, const float* __restrict__ bias1,
                       float* __restrict__ pooled_all) {
  int f = blockIdx.x * 256 + threadIdx.x;  // 0..1023
  int z = blockIdx.z;
  int g = z >> 5, b = z & 31;
  const unsigned short* agg = agg_all + (size_t)g * N_NODES * F_;
  const float* bias = g ? bias1 : bias0;
  float* pooled = pooled_all + (size_t)g * B_ * F_;
  int r0 = blockIdx.y * 100;
  float bf = bias[f];
  float s = 0.f;
  for (int r = 0; r < 100; ++r)
    s += leaky(bf2f(agg[(size_t)(b * NPG_ + r0 + r) * F_ + f]) + bf);
  atomicAdd(&pooled[b * F_ + f], s);
}

// ---- fc (grid.y = graph) ----
__global__ void k_fc(const float* __restrict__ pooled_all,
                     const float* __restrict__ w0, const float* __restrict__ w1,
                     const float* __restrict__ bias0, const float* __restrict__ bias1,
                     float* __restrict__ out0, float* __restrict__ out1) {
  int b = blockIdx.x, o = threadIdx.x, g = blockIdx.y;
  const float* p  = pooled_all + (size_t)g * B_ * F_ + b * F_;
  const float* wr = (g ? w1 : w0) + o * F_;
  const float* bias = g ? bias1 : bias0;
  float* out = g ? out1 : out0;
  float acc = 0.f;
  for (int f = 0; f < F_; ++f) acc += p[f] * wr[f];
  out[b * OD_ + o] = leaky(acc * (1.f / 500.f) + bias[o]);
}

// ---- ragged pack ----
__global__ void k_pack(const float* __restrict__ m0, const float* __restrict__ m1,
                       const float* __restrict__ m2, const float* __restrict__ m3,
                       const int* __restrict__ l0, const int* __restrict__ l1,
                       const int* __restrict__ l2, const int* __restrict__ l3,
                       const float* __restrict__ rw, const float* __restrict__ rb,
                       float* __restrict__ seq) {
  __shared__ float xs[DD_];
  const int p = blockIdx.x, b = blockIdx.y, k = blockIdx.z;
  const float* mas = (k == 0) ? m0 : (k == 1) ? m1 : (k == 2) ? m2 : m3;
  const int*   lk  = (k == 0) ? l0 : (k == 1) ? l1 : (k == 2) ? l2 : l3;
  const int len = lk[b];
  if (p >= len) return;
  int off = 0;
  if (k > 0) off += l0[b];
  if (k > 1) off += l1[b];
  if (k > 2) off += l2[b];
  const int t = threadIdx.x;  // 64
  for (int d = t; d < DD_; d += 64) xs[d] = mas[(size_t)(b * LSUB_ + p) * DD_ + d];
  __syncthreads();
  if (t < TD_) {
    float v;
    if (t < TD_ - 2) {
      float a = rb[t];
      const float* w = &rw[t * DD_];
      for (int d = 0; d < DD_; ++d) a += xs[d] * w[d];
      v = a;
    } else if (t == TD_ - 2) {
      v = (k == 0 || k == 2) ? 1.f : 0.f;
    } else {
      v = (k < 2) ? 1.f : 0.f;
    }
    seq[((size_t)b * MAXLEN_ + off + p) * TD_ + t] = v;
  }
}

__global__ void k_totlen(const int* __restrict__ l0, const int* __restrict__ l1,
                         const int* __restrict__ l2, const int* __restrict__ l3,
                         int* __restrict__ tot) {
  int b = threadIdx.x;
  if (b < B_) tot[b] = l0[b] + l1[b] + l2[b] + l3[b];
}

// ---- qkv projection (skip dead rows) ----
__global__ void k_qkv(const float* __restrict__ xt, const float* __restrict__ w,
                      const float* __restrict__ bias, const int* __restrict__ tot,
                      float* __restrict__ qkv) {
  __shared__ float xs[TD_];
  const int row = blockIdx.x;
  if ((row & (MAXLEN_ - 1)) >= tot[row >> 9]) return;
  const int t = threadIdx.x;      // 128
  if (t < TD_) xs[t] = xt[(size_t)row * TD_ + t];
  __syncthreads();
  if (t < 3 * TD_) {
    float a = bias[t];
    const float* wr = &w[t * TD_];
#pragma unroll
    for (int k = 0; k < TD_; ++k) a += xs[k] * wr[k];
    qkv[(size_t)row * 96 + t] = a;
  }
}

// ---- attention: one lane-pair per query, single pass (scores |s|<~1) ----
__global__ __launch_bounds__(128) void k_attn(const float* __restrict__ qkv,
                                              const int* __restrict__ tot,
                                              float* __restrict__ obuf) {
  __shared__ float Kl[MAXLEN_ * DH_];
  __shared__ float Vl[MAXLEN_ * DH_];
  const int h = blockIdx.x, b = blockIdx.y, qz = blockIdx.z;
  const int t = threadIdx.x;  // 128
  const int L = tot[b];
  if (qz * 64 >= L) return;
  const float* base = &qkv[(size_t)b * MAXLEN_ * 96];
  for (int i = t; i < L * DH_; i += 128) {
    int p = i >> 3, d = i & 7;
    Kl[i] = base[p * 96 + 32 + h * 8 + d];
    Vl[i] = base[p * 96 + 64 + h * 8 + d];
  }
  __syncthreads();
  const int qi = qz * 64 + (t >> 1);
  if (qi >= L) return;
  const int half = t & 1;
  const float scale = 0.35355339059327373f;  // 1/sqrt(8)
  float q[8];
#pragma unroll
  for (int d = 0; d < 8; ++d) q[d] = base[qi * 96 + h * 8 + d] * scale;

  float l0 = 0.f, l1 = 0.f;
  float a0[8] = {0, 0, 0, 0, 0, 0, 0, 0};
  float a1[8] = {0, 0, 0, 0, 0, 0, 0, 0};
  int j = half;
  for (; j + 2 < L; j += 4) {
    const float* kr0 = &Kl[j * 8];
    const float* kr1 = &Kl[(j + 2) * 8];
    float s0 = 0.f, s1 = 0.f;
#pragma unroll
    for (int d = 0; d < 8; ++d) { s0 += q[d] * kr0[d]; s1 += q[d] * kr1[d]; }
    float p0 = __expf(s0), p1 = __expf(s1);
    l0 += p0; l1 += p1;
    const float* vr0 = &Vl[j * 8];
    const float* vr1 = &Vl[(j + 2) * 8];
#pragma unroll
    for (int d = 0; d < 8; ++d) { a0[d] += p0 * vr0[d]; a1[d] += p1 * vr1[d]; }
  }
  for (; j < L; j += 2) {
    const float* kr = &Kl[j * 8];
    float s = 0.f;
#pragma unroll
    for (int d = 0; d < 8; ++d) s += q[d] * kr[d];
    float p = __expf(s);
    l0 += p;
    const float* vr = &Vl[j * 8];
#pragma unroll
    for (int d = 0; d < 8; ++d) a0[d] += p * vr[d];
  }
  float l = l0 + l1;
#pragma unroll
  for (int d = 0; d < 8; ++d) a0[d] += a1[d];
  l += __shfl_xor(l, 1);
#pragma unroll
  for (int d = 0; d < 8; ++d) a0[d] += __shfl_xor(a0[d], 1);
  float inv = 1.f / l;
  const int dbase = half * 4;
  float4 o;
  o.x = a0[dbase + 0] * inv; o.y = a0[dbase + 1] * inv;
  o.z = a0[dbase + 2] * inv; o.w = a0[dbase + 3] * inv;
  *(float4*)&obuf[((size_t)b * MAXLEN_ + qi) * TD_ + h * 8 + dbase] = o;
}

// ---- out-proj + residual + LN1 (skip dead rows) ----
__global__ void k_oproj_ln(const float* __restrict__ obuf, const float* __restrict__ w,
                           const float* __restrict__ bias, const float* __restrict__ lw,
                           const float* __restrict__ lb, const int* __restrict__ tot,
                           float* __restrict__ xt) {
  const int t = threadIdx.x;             // 256
  const int r = blockIdx.x * 8 + (t >> 5);
  if ((r & (MAXLEN_ - 1)) >= tot[r >> 9]) return;
  const int j = t & 31;
  const float* orow = &obuf[(size_t)r * TD_];
  float a = bias[j] + xt[(size_t)r * TD_ + j];
  const float* wr = &w[j * TD_];
#pragma unroll
  for (int k = 0; k < TD_; ++k) a += orow[k] * wr[k];
  float s1 = a, s2 = a * a;
#pragma unroll
  for (int m = 1; m < 32; m <<= 1) {
    s1 += __shfl_xor(s1, m, 32);
    s2 += __shfl_xor(s2, m, 32);
  }
  float mean = s1 * (1.f / 32.f);
  float var  = s2 * (1.f / 32.f) - mean * mean;
  xt[(size_t)r * TD_ + j] = (a - mean) * rsqrtf(var + EPS_) * lw[j] + lb[j];
}

// ---- FFN (relu) + residual + LN2 (skip dead rows) ----
__global__ void k_ffn_ln(const float* __restrict__ w1, const float* __restrict__ b1,
                         const float* __restrict__ w2, const float* __restrict__ b2,
                         const float* __restrict__ lw, const float* __restrict__ lb,
                         const int* __restrict__ tot, float* __restrict__ xt) {
  const int r = blockIdx.x, t = threadIdx.x;  // 128
  if ((r & (MAXLEN_ - 1)) >= tot[r >> 9]) return;
  __shared__ float xs[TD_];
  __shared__ float hb[DFF_];
  if (t < TD_) xs[t] = xt[(size_t)r * TD_ + t];
  __syncthreads();
  {
    float a = b1[t];
    const float* wr = &w1[t * TD_];
#pragma unroll
    for (int k = 0; k < TD_; ++k) a += xs[k] * wr[k];
    hb[t] = fmaxf(a, 0.f);
  }
  __syncthreads();
  if (t < TD_) {
    float a = b2[t] + xs[t];
    const float* wr = &w2[t * DFF_];
#pragma unroll
    for (int k = 0; k < DFF_; ++k) a += hb[k] * wr[k];
    float s1 = a, s2 = a * a;
#pragma unroll
    for (int m = 1; m < 32; m <<= 1) {
      s1 += __shfl_xor(s1, m, 32);
      s2 += __shfl_xor(s2, m, 32);
    }
    float mean = s1 * (1.f / 32.f);
    float var  = s2 * (1.f / 32.f) - mean * mean;
    xt[(size_t)r * TD_ + t] = (a - mean) * rsqrtf(var + EPS_) * lw[t] + lb[t];
  }
}

// ---- masked mean ----
__global__ void k_maskmean(const float* __restrict__ xt, const int* __restrict__ tot,
                           float* __restrict__ mout) {
  __shared__ float sbuf[8][32];
  const int b = blockIdx.x, t = threadIdx.x;  // 256
  const int j = t & 31, c = t >> 5;
  const int L = tot[b];
  float s = 0.f;
  for (int p = c; p < L; p += 8) s += xt[((size_t)b * MAXLEN_ + p) * TD_ + j];
  sbuf[c][j] = s;
  __syncthreads();
  if (t < 32) {
    float a = 0.f;
#pragma unroll
    for (int cc = 0; cc < 8; ++cc) a += sbuf[cc][t];
    mout[b * TD_ + t] = a / (float)L;
  }
}

// ---- final linear ----
__global__ void k_final(const float* __restrict__ x1, const float* __restrict__ x2,
                        const float* __restrict__ mo, const float* __restrict__ fw,
                        const float* __restrict__ fb, float* __restrict__ out) {
  const int b = blockIdx.x, t = threadIdx.x;  // 64
  float s = 0.f;
  for (int i = t; i < 2 * OD_ + TD_; i += 64) {
    float c = (i < OD_) ? x1[b * OD_ + i]
            : (i < 2 * OD_) ? x2[b * OD_ + (i - OD_)]
            : mo[b * TD_ + (i - 2 * OD_)];
    s += fw[i] * c;
  }
#pragma unroll
  for (int m = 1; m < 64; m <<= 1) s += __shfl_xor(s, m, 64);
  if (t == 0) out[b] = s + fb[0];
}

extern "C" void kernel_launch(void* const* d_in, const int* in_sizes, int n_in,
                              void* d_out, int out_size, void* d_ws, size_t ws_size,
                              hipStream_t stream) {
  (void)in_sizes; (void)n_in; (void)out_size; (void)ws_size;
  const float* pro_x[2]  = {(const float*)d_in[0], (const float*)d_in[1]};
  const int*   pro_ei[2] = {(const int*)d_in[2], (const int*)d_in[3]};
  const float* mas[4]    = {(const float*)d_in[6], (const float*)d_in[8],
                            (const float*)d_in[10], (const float*)d_in[12]};
  const int*   lens[4]   = {(const int*)d_in[7], (const int*)d_in[9],
                            (const int*)d_in[11], (const int*)d_in[13]};
  const float* gw[2]  = {(const float*)d_in[14], (const float*)d_in[16]};
  const float* gb[2]  = {(const float*)d_in[15], (const float*)d_in[17]};
  const float* fcw[2] = {(const float*)d_in[18], (const float*)d_in[20]};
  const float* fcb[2] = {(const float*)d_in[19], (const float*)d_in[21]};
  const float* red_w = (const float*)d_in[22];
  const float* red_b = (const float*)d_in[23];
  const float* attn_in_w  = (const float*)d_in[24];
  const float* attn_in_b  = (const float*)d_in[25];
  const float* attn_out_w = (const float*)d_in[26];
  const float* attn_out_b = (const float*)d_in[27];
  const float* ln1_w = (const float*)d_in[28];
  const float* ln1_b = (const float*)d_in[29];
  const float* ln2_w = (const float*)d_in[30];
  const float* ln2_b = (const float*)d_in[31];
  const float* ff1_w = (const float*)d_in[32];
  const float* ff1_b = (const float*)d_in[33];
  const float* ff2_w = (const float*)d_in[34];
  const float* ff2_b = (const float*)d_in[35];
  const float* final_w = (const float*)d_in[36];
  const float* final_b = (const float*)d_in[37];
  float* out = (float*)d_out;

  char* p = (char*)d_ws;
  auto carve = [&](size_t bytes) -> void* {
    void* r = (void*)p;
    p += (bytes + 255) & ~(size_t)255;
    return r;
  };
  unsigned short* xb  = (unsigned short*)carve((size_t)2 * N_NODES * F_ * 2);
  unsigned short* Wb  = (unsigned short*)carve((size_t)2 * F_ * F_ * 2);
  unsigned short* h   = (unsigned short*)carve((size_t)2 * N_NODES * F_ * 2);
  unsigned short* agg = (unsigned short*)carve((size_t)2 * N_NODES * F_ * 2);
  int*   cnt      = (int*)carve((size_t)2 * N_NODES * 4);
  float* dinv     = (float*)carve((size_t)2 * N_NODES * 4);
  int*   rowstart = (int*)carve((size_t)2 * (N_NODES + 1) * 4);
  int*   cursor   = (int*)carve((size_t)2 * N_NODES * 4);
  int*   csr      = (int*)carve((size_t)2 * E_ * 4);
  float* csrw     = (float*)carve((size_t)2 * E_ * 4);
  float* pooled   = (float*)carve((size_t)2 * B_ * F_ * 4);
  float* xg[2];
  xg[0] = (float*)carve((size_t)B_ * OD_ * 4);
  xg[1] = (float*)carve((size_t)B_ * OD_ * 4);
  float* seq    = (float*)carve((size_t)B_ * MAXLEN_ * TD_ * 4);
  float* qkv    = (float*)carve((size_t)B_ * MAXLEN_ * 96 * 4);
  float* obuf   = (float*)carve((size_t)B_ * MAXLEN_ * TD_ * 4);
  int*   totlen = (int*)carve((size_t)B_ * 4);
  float* masout = (float*)carve((size_t)B_ * TD_ * 4);

  // ---- GCN branches (merged across both graphs) ----
  k_f2bf2<<<dim3(1024, 2), 256, 0, stream>>>(pro_x[0], pro_x[1], xb,
                                             xb + (size_t)N_NODES * F_, (N_NODES * F_) / 4);
  k_f2bf2<<<dim3(512, 2), 256, 0, stream>>>(gw[0], gw[1], Wb, Wb + (size_t)F_ * F_,
                                            (F_ * F_) / 4);
  k_gemm_bf16<<<dim3(125, 8, 2), 256, 0, stream>>>(xb, Wb, h);
  hipMemsetAsync(cnt, 0, (size_t)2 * N_NODES * 4, stream);
  k_hist<<<dim3(1000, 2), 256, 0, stream>>>(pro_ei[0], pro_ei[1], cnt, E_, N_NODES);
  k_scan<<<2, 256, 0, stream>>>(cnt, rowstart, cursor, dinv, N_NODES);
  k_scatter<<<dim3(1000, 2), 256, 0, stream>>>(pro_ei[0], pro_ei[1], dinv, cursor,
                                               csr, csrw, E_, N_NODES);
  // gathers sequential per graph: keeps per-XCD h working set at one 4 MB slice
  for (int g = 0; g < 2; ++g) {
    k_gather<<<dim3(8, N_NODES), 64, 0, stream>>>(
        (const ushort2*)(h + (size_t)g * N_NODES * F_), dinv + (size_t)g * N_NODES,
        rowstart + (size_t)g * (N_NODES + 1), csr + (size_t)g * E_, csrw + (size_t)g * E_,
        (ushort2*)(agg + (size_t)g * N_NODES * F_));
  }
  hipMemsetAsync(pooled, 0, (size_t)2 * B_ * F_ * 4, stream);
  k_pool<<<dim3(4, 5, 64), 256, 0, stream>>>(agg, gb[0], gb[1], pooled);
  k_fc<<<dim3(B_, 2), 128, 0, stream>>>(pooled, fcw[0], fcw[1], fcb[0], fcb[1],
                                        xg[0], xg[1]);

  // ---- ragged pack ----
  hipMemsetAsync(seq, 0, (size_t)B_ * MAXLEN_ * TD_ * 4, stream);
  k_pack<<<dim3(LSUB_, B_, 4), 64, 0, stream>>>(mas[0], mas[1], mas[2], mas[3],
                                                lens[0], lens[1], lens[2], lens[3],
                                                red_w, red_b, seq);
  k_totlen<<<1, 64, 0, stream>>>(lens[0], lens[1], lens[2], lens[3], totlen);

  // ---- transformer (2 layers) ----
  for (int li = 0; li < 2; ++li) {
    k_qkv<<<B_ * MAXLEN_, 128, 0, stream>>>(seq, attn_in_w + (size_t)li * 96 * TD_,
                                            attn_in_b + (size_t)li * 96, totlen, qkv);
    k_attn<<<dim3(NH_, B_, 8), 128, 0, stream>>>(qkv, totlen, obuf);
    k_oproj_ln<<<(B_ * MAXLEN_) / 8, 256, 0, stream>>>(
        obuf, attn_out_w + (size_t)li * TD_ * TD_, attn_out_b + (size_t)li * TD_,
        ln1_w + (size_t)li * TD_, ln1_b + (size_t)li * TD_, totlen, seq);
    k_ffn_ln<<<B_ * MAXLEN_, 128, 0, stream>>>(
        ff1_w + (size_t)li * DFF_ * TD_, ff1_b + (size_t)li * DFF_,
        ff2_w + (size_t)li * TD_ * DFF_, ff2_b + (size_t)li * TD_,
        ln2_w + (size_t)li * TD_, ln2_b + (size_t)li * TD_, totlen, seq);
  }

  // ---- masked mean + final ----
  k_maskmean<<<B_, 256, 0, stream>>>(seq, totlen, masout);
  k_final<<<B_, 64, 0, stream>>>(xg[0], xg[1], masout, final_w, final_b, out);
}